// Round 1
// baseline (15.667 us; speedup 1.0000x reference)
//
#include <hip/hip_runtime.h>
#include <hip/hip_bf16.h>
#include <math.h>

// Output is batch-independent: the circuit ignores x; feats = tile(ev,196) is
// identical for every batch row, so log_softmax(logits) is one 10-vector
// repeated B times. Kernel 1 computes those 10 values; kernel 2 broadcasts.

__device__ inline void pair_ev(float a0, float b0, float a1, float b1,
                               float* z0, float* z1) {
    // Simulate: |00> -> [CNOT (RY(a)⊗RY(b))]^2 with per-layer angles.
    float st[4] = {1.f, 0.f, 0.f, 0.f};
    float angs[2][2] = {{a0, b0}, {a1, b1}};
    #pragma unroll
    for (int L = 0; L < 2; ++L) {
        float c0, s0, c1, s1;
        __sincosf(angs[L][0] * 0.5f, &s0, &c0);
        __sincosf(angs[L][1] * 0.5f, &s1, &c1);
        float A[2][2]  = {{c0, -s0}, {s0, c0}};
        float Bm[2][2] = {{c1, -s1}, {s1, c1}};
        float ns[4];
        #pragma unroll
        for (int i1 = 0; i1 < 2; ++i1)
            #pragma unroll
            for (int j1 = 0; j1 < 2; ++j1) {
                float acc = 0.f;
                #pragma unroll
                for (int i0 = 0; i0 < 2; ++i0)
                    #pragma unroll
                    for (int j0 = 0; j0 < 2; ++j0)
                        acc += A[i1][i0] * Bm[j1][j0] * st[2 * i0 + j0];
                ns[2 * i1 + j1] = acc;
            }
        // CNOT(control=first qubit, target=second): swap |10> <-> |11>
        st[0] = ns[0]; st[1] = ns[1]; st[2] = ns[3]; st[3] = ns[2];
    }
    float p0 = st[0] * st[0], p1 = st[1] * st[1];
    float p2 = st[2] * st[2], p3 = st[3] * st[3];
    *z0 = p0 + p1 - p2 - p3;
    *z1 = p0 - p1 + p2 - p3;
}

// One block, 64 threads. Threads 0..39: column sums of W (class j, phase q).
// Thread 0 then finishes the tiny scalar tail (circuit + logits + log_softmax).
__global__ void quanv_logits_kernel(const float* __restrict__ params,
                                    const float* __restrict__ W,
                                    const float* __restrict__ b,
                                    float* __restrict__ out10) {
    __shared__ float s[40];
    int t = threadIdx.x;
    if (t < 40) {
        int j = t >> 2;        // class 0..9
        int q = t & 3;         // phase 0..3
        const float* wrow = W + j * 784 + q;
        float acc = 0.f;
        #pragma unroll 4
        for (int p = 0; p < 196; ++p) acc += wrow[4 * p];
        s[t] = acc;
    }
    __syncthreads();
    if (t == 0) {
        float ev[4];
        // params shape (2,4) row-major: params[layer*4 + wire]
        pair_ev(params[0], params[1], params[4], params[5], &ev[0], &ev[1]);
        pair_ev(params[2], params[3], params[6], params[7], &ev[2], &ev[3]);
        float logits[10];
        float m = -INFINITY;
        #pragma unroll
        for (int j = 0; j < 10; ++j) {
            float l = b[j] + ev[0] * s[4 * j + 0] + ev[1] * s[4 * j + 1]
                           + ev[2] * s[4 * j + 2] + ev[3] * s[4 * j + 3];
            logits[j] = l;
            m = fmaxf(m, l);
        }
        float sum = 0.f;
        #pragma unroll
        for (int j = 0; j < 10; ++j) sum += expf(logits[j] - m);
        float lse = m + logf(sum);
        #pragma unroll
        for (int j = 0; j < 10; ++j) out10[j] = logits[j] - lse;
    }
}

// Broadcast the 10-float pattern across B*10 floats with float4 stores.
__global__ void quanv_bcast_kernel(const float* __restrict__ v10,
                                   float4* __restrict__ out, int n4) {
    float v[10];
    #pragma unroll
    for (int k = 0; k < 10; ++k) v[k] = v10[k];
    int stride = gridDim.x * blockDim.x;
    for (int i = blockIdx.x * blockDim.x + threadIdx.x; i < n4; i += stride) {
        int base = (i * 4) % 10;
        float4 o;
        o.x = v[base];
        o.y = v[(base + 1) % 10];
        o.z = v[(base + 2) % 10];
        o.w = v[(base + 3) % 10];
        out[i] = o;
    }
}

extern "C" void kernel_launch(void* const* d_in, const int* in_sizes, int n_in,
                              void* d_out, int out_size, void* d_ws, size_t ws_size,
                              hipStream_t stream) {
    // Inputs (setup_inputs order): x [B,1,28,28] (UNUSED), params [2,4],
    // W [10,784], b [10]. Output: [B,10] float32, B = out_size/10.
    const float* params = (const float*)d_in[1];
    const float* W      = (const float*)d_in[2];
    const float* b      = (const float*)d_in[3];
    float* out   = (float*)d_out;
    float* out10 = (float*)d_ws;   // 10 floats of scratch

    quanv_logits_kernel<<<1, 64, 0, stream>>>(params, W, b, out10);

    int n4 = out_size / 4;                       // 81920 float4 stores
    int block = 256;
    int grid = (n4 + block - 1) / block;         // 320 blocks
    quanv_bcast_kernel<<<grid, block, 0, stream>>>(out10, (float4*)out, n4);
}

// Round 2
// 9.868 us; speedup vs baseline: 1.5877x; 1.5877x over previous
//
#include <hip/hip_runtime.h>
#include <hip/hip_bf16.h>
#include <math.h>

// Output is batch-independent: the circuit ignores x; feats = tile(ev,196) is
// identical for every row, so log_softmax(logits) is one 10-vector repeated
// B times. ONE fused kernel: every block redundantly computes the 10 values
// (W is 31KB -> L2-resident; cost ~hundreds of cycles), then writes its slice.

__device__ inline void pair_ev(float a0, float b0, float a1, float b1,
                               float* z0, float* z1) {
    // Simulate: |00> -> [CNOT (RY(a)⊗RY(b))]^2 with per-layer angles.
    float st[4] = {1.f, 0.f, 0.f, 0.f};
    float angs[2][2] = {{a0, b0}, {a1, b1}};
    #pragma unroll
    for (int L = 0; L < 2; ++L) {
        float c0, s0, c1, s1;
        __sincosf(angs[L][0] * 0.5f, &s0, &c0);
        __sincosf(angs[L][1] * 0.5f, &s1, &c1);
        float A[2][2]  = {{c0, -s0}, {s0, c0}};
        float Bm[2][2] = {{c1, -s1}, {s1, c1}};
        float ns[4];
        #pragma unroll
        for (int i1 = 0; i1 < 2; ++i1)
            #pragma unroll
            for (int j1 = 0; j1 < 2; ++j1) {
                float acc = 0.f;
                #pragma unroll
                for (int i0 = 0; i0 < 2; ++i0)
                    #pragma unroll
                    for (int j0 = 0; j0 < 2; ++j0)
                        acc += A[i1][i0] * Bm[j1][j0] * st[2 * i0 + j0];
                ns[2 * i1 + j1] = acc;
            }
        // CNOT(control=first qubit, target=second): swap |10> <-> |11>
        st[0] = ns[0]; st[1] = ns[1]; st[2] = ns[3]; st[3] = ns[2];
    }
    float p0 = st[0] * st[0], p1 = st[1] * st[1];
    float p2 = st[2] * st[2], p3 = st[3] * st[3];
    *z0 = p0 + p1 - p2 - p3;
    *z1 = p0 - p1 + p2 - p3;
}

// 256 threads/block. Threads 0..159: 16-way-split float4 dot of ev with class
// j's W row (196 float4s). Threads 0..9 finish logits; thread 0 does the lse.
// Then all 256 threads write one float4 of the broadcast output.
__global__ void __launch_bounds__(256)
quanv_fused_kernel(const float* __restrict__ params,
                   const float* __restrict__ W,
                   const float* __restrict__ b,
                   float4* __restrict__ out, int n4) {
    __shared__ float part[160];
    __shared__ float lj[10];
    __shared__ float fin[10];

    int t = threadIdx.x;

    // ev: pure scalar math from params, computed redundantly by threads that
    // need it (cheap, ~100 cycles, no divergence cost worth optimizing).
    float ev[4];
    pair_ev(params[0], params[1], params[4], params[5], &ev[0], &ev[1]);
    pair_ev(params[2], params[3], params[6], params[7], &ev[2], &ev[3]);
    float4 ev4 = make_float4(ev[0], ev[1], ev[2], ev[3]);

    if (t < 160) {
        int j = t >> 4;        // class 0..9
        int k = t & 15;        // chunk lane 0..15
        const float4* w4 = (const float4*)W + j * 196;
        float acc = 0.f;
        for (int p = k; p < 196; p += 16) {
            float4 w = w4[p];
            acc += ev4.x * w.x + ev4.y * w.y + ev4.z * w.z + ev4.w * w.w;
        }
        part[t] = acc;
    }
    __syncthreads();
    if (t < 10) {
        float acc = b[t];
        #pragma unroll
        for (int k = 0; k < 16; ++k) acc += part[t * 16 + k];
        lj[t] = acc;
    }
    __syncthreads();
    if (t == 0) {
        float m = -INFINITY;
        #pragma unroll
        for (int j = 0; j < 10; ++j) m = fmaxf(m, lj[j]);
        float sum = 0.f;
        #pragma unroll
        for (int j = 0; j < 10; ++j) sum += expf(lj[j] - m);
        float lse = m + logf(sum);
        #pragma unroll
        for (int j = 0; j < 10; ++j) fin[j] = lj[j] - lse;
    }
    __syncthreads();

    float v[10];
    #pragma unroll
    for (int k = 0; k < 10; ++k) v[k] = fin[k];

    int i = blockIdx.x * blockDim.x + t;   // global float4 index
    if (i < n4) {
        int base = (i * 4) % 10;
        float4 o;
        o.x = v[base];
        o.y = v[(base + 1) % 10];
        o.z = v[(base + 2) % 10];
        o.w = v[(base + 3) % 10];
        out[i] = o;
    }
}

extern "C" void kernel_launch(void* const* d_in, const int* in_sizes, int n_in,
                              void* d_out, int out_size, void* d_ws, size_t ws_size,
                              hipStream_t stream) {
    // Inputs (setup_inputs order): x [B,1,28,28] (UNUSED), params [2,4],
    // W [10,784], b [10]. Output: [B,10] float32, B = out_size/10.
    const float* params = (const float*)d_in[1];
    const float* W      = (const float*)d_in[2];
    const float* b      = (const float*)d_in[3];
    float* out = (float*)d_out;

    int n4 = out_size / 4;                       // 81920 float4 stores
    int block = 256;
    int grid = (n4 + block - 1) / block;         // 320 blocks
    quanv_fused_kernel<<<grid, block, 0, stream>>>(params, W, b,
                                                   (float4*)out, n4);
}

// Round 3
// 9.705 us; speedup vs baseline: 1.6144x; 1.0168x over previous
//
#include <hip/hip_runtime.h>
#include <hip/hip_bf16.h>
#include <math.h>

// Output is batch-independent: the circuit ignores x; feats = tile(ev,196) is
// identical for every row, so log_softmax(logits) is one 10-vector repeated
// B times. ONE fused kernel, ONE barrier: shfl-reduced partial dots -> LDS
// logits -> every thread redundantly finishes log_softmax -> float4 write.

__device__ inline void pair_ev(float a0, float b0, float a1, float b1,
                               float* z0, float* z1) {
    // Simulate: |00> -> [CNOT (RY(a)⊗RY(b))]^2 with per-layer angles.
    float st[4] = {1.f, 0.f, 0.f, 0.f};
    float angs[2][2] = {{a0, b0}, {a1, b1}};
    #pragma unroll
    for (int L = 0; L < 2; ++L) {
        float c0, s0, c1, s1;
        __sincosf(angs[L][0] * 0.5f, &s0, &c0);
        __sincosf(angs[L][1] * 0.5f, &s1, &c1);
        float A[2][2]  = {{c0, -s0}, {s0, c0}};
        float Bm[2][2] = {{c1, -s1}, {s1, c1}};
        float ns[4];
        #pragma unroll
        for (int i1 = 0; i1 < 2; ++i1)
            #pragma unroll
            for (int j1 = 0; j1 < 2; ++j1) {
                float acc = 0.f;
                #pragma unroll
                for (int i0 = 0; i0 < 2; ++i0)
                    #pragma unroll
                    for (int j0 = 0; j0 < 2; ++j0)
                        acc += A[i1][i0] * Bm[j1][j0] * st[2 * i0 + j0];
                ns[2 * i1 + j1] = acc;
            }
        // CNOT(control=first qubit, target=second): swap |10> <-> |11>
        st[0] = ns[0]; st[1] = ns[1]; st[2] = ns[3]; st[3] = ns[2];
    }
    float p0 = st[0] * st[0], p1 = st[1] * st[1];
    float p2 = st[2] * st[2], p3 = st[3] * st[3];
    *z0 = p0 + p1 - p2 - p3;
    *z1 = p0 - p1 + p2 - p3;
}

__global__ void __launch_bounds__(256)
quanv_fused_kernel(const float* __restrict__ params,
                   const float* __restrict__ W,
                   const float* __restrict__ b,
                   float4* __restrict__ out, int n4) {
    __shared__ float lj[10];

    int t = threadIdx.x;
    int j = t >> 4;        // class 0..9 (for t<160)
    int k = t & 15;        // chunk lane 0..15

    // ev: redundant scalar math from params (cheap, fully parallel).
    float ev[4];
    pair_ev(params[0], params[1], params[4], params[5], &ev[0], &ev[1]);
    pair_ev(params[2], params[3], params[6], params[7], &ev[2], &ev[3]);

    // Partial dot: class j's W row is 196 float4s, split 16 ways.
    float acc = 0.f;
    if (t < 160) {
        const float4* w4 = (const float4*)W + j * 196;
        #pragma unroll 4
        for (int p = k; p < 196; p += 16) {
            float4 w = w4[p];
            acc += ev[0] * w.x + ev[1] * w.y + ev[2] * w.z + ev[3] * w.w;
        }
    }
    // In-wave reduce over each aligned 16-lane group (no LDS round trip).
    acc += __shfl_xor(acc, 1);
    acc += __shfl_xor(acc, 2);
    acc += __shfl_xor(acc, 4);
    acc += __shfl_xor(acc, 8);
    if (t < 160 && k == 0) lj[j] = acc + b[j];
    __syncthreads();

    // Every thread redundantly finishes log_softmax (parallel, no serial tail).
    float v[10];
    float m = -INFINITY;
    #pragma unroll
    for (int c = 0; c < 10; ++c) { v[c] = lj[c]; m = fmaxf(m, v[c]); }
    float sum = 0.f;
    #pragma unroll
    for (int c = 0; c < 10; ++c) sum += expf(v[c] - m);
    float lse = m + logf(sum);
    #pragma unroll
    for (int c = 0; c < 10; ++c) v[c] -= lse;

    int i = blockIdx.x * blockDim.x + t;   // global float4 index
    if (i < n4) {
        int base = (i * 4) % 10;
        float4 o;
        o.x = v[base];
        o.y = v[(base + 1) % 10];
        o.z = v[(base + 2) % 10];
        o.w = v[(base + 3) % 10];
        out[i] = o;
    }
}

extern "C" void kernel_launch(void* const* d_in, const int* in_sizes, int n_in,
                              void* d_out, int out_size, void* d_ws, size_t ws_size,
                              hipStream_t stream) {
    // Inputs (setup_inputs order): x [B,1,28,28] (UNUSED), params [2,4],
    // W [10,784], b [10]. Output: [B,10] float32, B = out_size/10.
    const float* params = (const float*)d_in[1];
    const float* W      = (const float*)d_in[2];
    const float* b      = (const float*)d_in[3];
    float* out = (float*)d_out;

    int n4 = out_size / 4;                       // 81920 float4 stores
    int block = 256;
    int grid = (n4 + block - 1) / block;         // 320 blocks
    quanv_fused_kernel<<<grid, block, 0, stream>>>(params, W, b,
                                                   (float4*)out, n4);
}